// Round 9
// baseline (192.146 us; speedup 1.0000x reference)
//
#include <hip/hip_runtime.h>
#include <hip/hip_bf16.h>

#define KN  2048   // nodes
#define KD  256    // emb dim = HF
#define KH  4      // heads
#define KF  64     // feat/head
#define KT  64     // time steps
#define NCS 32     // colsum partial buffers
#define MAXE 256

typedef __attribute__((ext_vector_type(8))) short short8;
typedef __attribute__((ext_vector_type(4))) float floatx4;

struct Args {
    const float *y, *adj, *emb;
    const float *pos_w, *pos_wu, *pos_wv, *pos_b, *pos_pw, *pos_pb;
    const float *neg_w, *neg_wu, *neg_wv, *neg_b, *neg_pw, *neg_pb;
    const float *self_w, *self_b;
    const float *mlp_pos_w, *mlp_pos_b, *mlp_neg_w, *mlp_neg_b;
    const float *sem_w1, *sem_b1, *sem_w2;
    float* out;
    unsigned char* code;
    float *ycs, *S_pos, *S_neg, *P_pos, *P_neg, *sup, *G, *X, *colsum;
    float *f1p, *f2p, *f1n, *f2n, *M0Wp, *M0Wn, *fbp, *fbn;
};

// ---------------- helpers ----------------
__device__ __forceinline__ float wave_sum(float v) {
    #pragma unroll
    for (int o = 32; o > 0; o >>= 1) v += __shfl_xor(v, o, 64);
    return v;
}
__device__ __forceinline__ float wave_max(float v) {
    #pragma unroll
    for (int o = 32; o > 0; o >>= 1) v = fmaxf(v, __shfl_xor(v, o, 64));
    return v;
}
__device__ __forceinline__ short f2bs(float x) {
    union { __hip_bfloat16 h; short s; } u;
    u.h = __float2bfloat16(x);
    return u.s;
}

// ---------------- K0: setup = ycs normalize (proven R5 structure) --------
__global__ __launch_bounds__(256) void setup_kernel(const float* __restrict__ y,
                                                    float* __restrict__ ycs) {
    int w = threadIdx.x >> 6, lane = threadIdx.x & 63;
    int n = blockIdx.x * 4 + w;
    float v = y[n * KT + lane];
    float mean = wave_sum(v) * (1.0f / KT);
    float yc = v - mean;
    float ss = wave_sum(yc * yc);
    ycs[n * KT + lane] = yc * rsqrtf(ss * (1.0f / (KT - 1)));
}

// ---------------- corr body: upper-tri 64x64 tile (R5 version) -----------
__device__ __forceinline__ void corr_body(const float* __restrict__ ycs,
                                          const float* __restrict__ adj,
                                          unsigned char* __restrict__ code,
                                          int blk, char* smem) {
    float (*As)[68] = (float(*)[68])smem;            // 16x68 f32
    float (*Bs)[68] = (float(*)[68])(smem + 4352);
    int bi = 0, rem = blk;
    while (rem >= 32 - bi) { rem -= 32 - bi; bi++; }
    int bj = bi + rem;
    int i0 = bi * 64, j0 = bj * 64;
    int t = threadIdx.x;
    int tx = t & 15, ty = t >> 4;
    int ar = t >> 2, ac = (t & 3) * 4;
    float acc[4][4] = {};
    for (int kt = 0; kt < KT; kt += 16) {
        float4 a4 = *reinterpret_cast<const float4*>(&ycs[(size_t)(i0 + ar) * KT + kt + ac]);
        float4 b4 = *reinterpret_cast<const float4*>(&ycs[(size_t)(j0 + ar) * KT + kt + ac]);
        As[ac + 0][ar] = a4.x; As[ac + 1][ar] = a4.y; As[ac + 2][ar] = a4.z; As[ac + 3][ar] = a4.w;
        Bs[ac + 0][ar] = b4.x; Bs[ac + 1][ar] = b4.y; Bs[ac + 2][ar] = b4.z; Bs[ac + 3][ar] = b4.w;
        __syncthreads();
        #pragma unroll
        for (int kk = 0; kk < 16; kk++) {
            float4 av = *reinterpret_cast<const float4*>(&As[kk][ty * 4]);
            float4 bv = *reinterpret_cast<const float4*>(&Bs[kk][tx * 4]);
            float a4v[4] = {av.x, av.y, av.z, av.w};
            float b4v[4] = {bv.x, bv.y, bv.z, bv.w};
            #pragma unroll
            for (int ii = 0; ii < 4; ii++)
                #pragma unroll
                for (int jj = 0; jj < 4; jj++) acc[ii][jj] += a4v[ii] * b4v[jj];
        }
        __syncthreads();
    }
    #pragma unroll
    for (int ii = 0; ii < 4; ii++) {
        int i = i0 + ty * 4 + ii;
        int jb = j0 + tx * 4;
        float4 av4 = *reinterpret_cast<const float4*>(&adj[(size_t)i * KN + jb]);
        float a4v[4] = {av4.x, av4.y, av4.z, av4.w};
        uchar4 cc;
        unsigned char* c = (unsigned char*)&cc;
        #pragma unroll
        for (int jj = 0; jj < 4; jj++)
            c[jj] = (a4v[jj] != 0.0f) ? ((acc[ii][jj] >= 0.1f) ? 1 : 2) : 0;
        *reinterpret_cast<uchar4*>(&code[(size_t)i * KN + jb]) = cc;
    }
    if (bi != bj) {
        #pragma unroll
        for (int jj = 0; jj < 4; jj++) {
            int j = j0 + tx * 4 + jj;
            int ib = i0 + ty * 4;
            float4 av4 = *reinterpret_cast<const float4*>(&adj[(size_t)j * KN + ib]);
            float a4v[4] = {av4.x, av4.y, av4.z, av4.w};
            uchar4 cc;
            unsigned char* c = (unsigned char*)&cc;
            #pragma unroll
            for (int ii = 0; ii < 4; ii++)
                c[ii] = (a4v[ii] != 0.0f) ? ((acc[ii][jj] >= 0.1f) ? 1 : 2) : 0;
            *reinterpret_cast<uchar4*>(&code[(size_t)j * KN + ib]) = cc;
        }
    }
}

// ---------------- MFMA bf16 GEMM body: 64x64 C tile, K=256 (phase1) -----
__device__ __forceinline__ void mfma_gemm_body(
    const float* __restrict__ A, int lda, int bm,
    const float* __restrict__ B, int ldb, int bn,
    const float* __restrict__ bias,
    float* __restrict__ C, int ldc, int cn,
    float* __restrict__ f1h, float* __restrict__ f2h,
    const float* __restrict__ wu_h, const float* __restrict__ wv_h,
    char* smem)
{
    short* As = (short*)smem;            // [64][40] bf16 (row m, col k)
    short* Bs = (short*)(smem + 5120);   // [64][40] bf16 (row n, col k) transposed
    int t = threadIdx.x;
    int w = t >> 6, lane = t & 63;
    int m16 = lane & 15, kq = lane >> 4;
    floatx4 acc0 = {0,0,0,0}, acc1 = {0,0,0,0}, acc2 = {0,0,0,0}, acc3 = {0,0,0,0};
    int ar = t >> 2, acq = (t & 3) * 8;
    int bnn = t & 63, bkg = (t >> 6) * 8;
    for (int kt = 0; kt < KD; kt += 32) {
        const float* pa = &A[(size_t)(bm + ar) * lda + kt + acq];
        float4 a0 = *(const float4*)pa;
        float4 a1 = *(const float4*)(pa + 4);
        short8 av;
        av[0] = f2bs(a0.x); av[1] = f2bs(a0.y); av[2] = f2bs(a0.z); av[3] = f2bs(a0.w);
        av[4] = f2bs(a1.x); av[5] = f2bs(a1.y); av[6] = f2bs(a1.z); av[7] = f2bs(a1.w);
        const float* pb = &B[(size_t)(kt + bkg) * ldb + bn + bnn];
        short8 bv;
        #pragma unroll
        for (int u = 0; u < 8; u++) bv[u] = f2bs(pb[(size_t)u * ldb]);
        __syncthreads();
        *(short8*)&As[ar * 40 + acq] = av;
        *(short8*)&Bs[bnn * 40 + bkg] = bv;
        __syncthreads();
        short8 af  = *(short8*)&As[(w * 16 + m16) * 40 + kq * 8];
        short8 bf0 = *(short8*)&Bs[( 0 + m16) * 40 + kq * 8];
        short8 bf1 = *(short8*)&Bs[(16 + m16) * 40 + kq * 8];
        short8 bf2 = *(short8*)&Bs[(32 + m16) * 40 + kq * 8];
        short8 bf3 = *(short8*)&Bs[(48 + m16) * 40 + kq * 8];
        acc0 = __builtin_amdgcn_mfma_f32_16x16x32_bf16(af, bf0, acc0, 0, 0, 0);
        acc1 = __builtin_amdgcn_mfma_f32_16x16x32_bf16(af, bf1, acc1, 0, 0, 0);
        acc2 = __builtin_amdgcn_mfma_f32_16x16x32_bf16(af, bf2, acc2, 0, 0, 0);
        acc3 = __builtin_amdgcn_mfma_f32_16x16x32_bf16(af, bf3, acc3, 0, 0, 0);
    }
    int row0 = bm + w * 16 + kq * 4;
    floatx4 accs[4] = {acc0, acc1, acc2, acc3};
    #pragma unroll
    for (int nb = 0; nb < 4; nb++) {
        #pragma unroll
        for (int r = 0; r < 4; r++) {
            int col = nb * 16 + m16;
            float v = accs[nb][r] + (bias ? bias[col] : 0.0f);
            C[(size_t)(row0 + r) * ldc + cn + col] = v;
        }
    }
    if (f1h) {
        float wuv[4], wvv[4];
        #pragma unroll
        for (int nb = 0; nb < 4; nb++) { wuv[nb] = wu_h[nb * 16 + m16]; wvv[nb] = wv_h[nb * 16 + m16]; }
        #pragma unroll
        for (int r = 0; r < 4; r++) {
            float p1 = accs[0][r] * wuv[0] + accs[1][r] * wuv[1] + accs[2][r] * wuv[2] + accs[3][r] * wuv[3];
            float p2 = accs[0][r] * wvv[0] + accs[1][r] * wvv[1] + accs[2][r] * wvv[2] + accs[3][r] * wvv[3];
            #pragma unroll
            for (int o = 1; o < 16; o <<= 1) {
                p1 += __shfl_xor(p1, o, 64);
                p2 += __shfl_xor(p2, o, 64);
            }
            if (m16 == 0) { f1h[row0 + r] = p1; f2h[row0 + r] = p2; }
        }
    }
}

// ---------------- fused bias unit: fb = mlp_b @ sem_w1 + sem_b1 ---------
__device__ __forceinline__ void fb_unit(const float* __restrict__ mb,
                                        const float* __restrict__ w1,
                                        const float* __restrict__ b1,
                                        float* __restrict__ fb) {
    int j = threadIdx.x;
    float acc = b1[j];
    for (int k = 0; k < KD; k++) acc = fmaf(mb[k], w1[(size_t)k * KD + j], acc);
    fb[j] = acc;
}

// ---- K1: phase1 = corr(528) + emb GEMMs(640) + M0W(32) + fb(2) + zero(1) --
__global__ __launch_bounds__(256, 4) void phase1_kernel(Args a) {
    __shared__ alignas(16) char smem[10240];
    int blk = blockIdx.x;
    if (blk < 528) { corr_body(a.ycs, a.adj, a.code, blk, smem); return; }
    if (blk < 1168) {
        int b = blk - 528;             // 0..639: 5 emb GEMMs x 4 coltiles x 32 rowtiles
        int tn = b % 20, tm = b / 20;
        int buf = tn >> 2, coloff = (tn & 3) * 64, h = tn & 3;
        const float* B; const float* bias = nullptr; float* C;
        float *f1h = nullptr, *f2h = nullptr;
        const float *wu = nullptr, *wv = nullptr;
        if (buf == 0) {
            B = a.pos_w; C = a.S_pos;
            f1h = a.f1p + h * KN; f2h = a.f2p + h * KN;
            wu = a.pos_wu + h * KF; wv = a.pos_wv + h * KF;
        } else if (buf == 1) {
            B = a.neg_w; C = a.S_neg;
            f1h = a.f1n + h * KN; f2h = a.f2n + h * KN;
            wu = a.neg_wu + h * KF; wv = a.neg_wv + h * KF;
        } else if (buf == 2) { B = a.pos_pw; bias = a.pos_pb + coloff; C = a.P_pos; }
        else if (buf == 3)   { B = a.neg_pw; bias = a.neg_pb + coloff; C = a.P_neg; }
        else                 { B = a.self_w; bias = a.self_b + coloff; C = a.sup; }
        mfma_gemm_body(a.emb, KD, tm * 64, B, KD, coloff, bias,
                       C, KD, coloff, f1h, f2h, wu, wv, smem);
        return;
    }
    if (blk < 1184) {   // M0Wp = mlp_pos_w @ sem_w1
        int v = blk - 1168;
        mfma_gemm_body(a.mlp_pos_w, KD, (v >> 2) * 64, a.sem_w1, KD, (v & 3) * 64,
                       nullptr, a.M0Wp, KD, (v & 3) * 64,
                       nullptr, nullptr, nullptr, nullptr, smem);
        return;
    }
    if (blk < 1200) {   // M0Wn = mlp_neg_w @ sem_w1
        int v = blk - 1184;
        mfma_gemm_body(a.mlp_neg_w, KD, (v >> 2) * 64, a.sem_w1, KD, (v & 3) * 64,
                       nullptr, a.M0Wn, KD, (v & 3) * 64,
                       nullptr, nullptr, nullptr, nullptr, smem);
        return;
    }
    if (blk == 1200) { fb_unit(a.mlp_pos_b, a.sem_w1, a.sem_b1, a.fbp); return; }
    if (blk == 1201) { fb_unit(a.mlp_neg_b, a.sem_w1, a.sem_b1, a.fbn); return; }
    // blk == 1202: zero colsum
    for (int j = threadIdx.x; j < NCS * KD; j += 256) a.colsum[j] = 0.0f;
}

// ---------------- K2: sparse GAT row, block per i, both rels, wave = head --
__global__ __launch_bounds__(256) void attn_kernel(Args a) {
    __shared__ alignas(16) int jl[2][MAXE];
    __shared__ alignas(16) float lg[KH][MAXE];
    __shared__ int cnt[2];
    int i = blockIdx.x;
    int w = threadIdx.x >> 6, lane = threadIdx.x & 63;
    if (threadIdx.x < 2) cnt[threadIdx.x] = 0;
    __syncthreads();
    #pragma unroll
    for (int it = 0; it < 2; it++) {
        int base = w * 512 + it * 256;
        uchar4 cv = *reinterpret_cast<const uchar4*>(&a.code[(size_t)i * KN + base + lane * 4]);
        const unsigned char* ce = (const unsigned char*)&cv;
        #pragma unroll
        for (int e = 0; e < 4; e++) {
            #pragma unroll
            for (int rel = 0; rel < 2; rel++) {
                bool pr = (ce[e] == (rel ? (unsigned char)2 : (unsigned char)1));
                unsigned long long bal = __ballot(pr);
                int tot = __popcll(bal);
                int basepos = 0;
                if (lane == 0 && tot) basepos = atomicAdd(&cnt[rel], tot);
                basepos = __shfl(basepos, 0, 64);
                if (pr) {
                    int idx = basepos + __popcll(bal & ((1ull << lane) - 1ull));
                    if (idx < MAXE) jl[rel][idx] = base + lane * 4 + e;
                }
            }
        }
    }
    __syncthreads();
    int c0 = cnt[0]; if (c0 > MAXE) c0 = MAXE;
    int c1 = cnt[1]; if (c1 > MAXE) c1 = MAXE;
    if (threadIdx.x < 4) {
        int cR = (c0 + 3) & ~3;
        if (c0 + threadIdx.x < cR) jl[0][c0 + threadIdx.x] = 0;
    } else if (threadIdx.x < 8) {
        int l2 = threadIdx.x - 4;
        int cR = (c1 + 3) & ~3;
        if (c1 + l2 < cR) jl[1][c1 + l2] = 0;
    }
    __syncthreads();
    int h = w;
    int g = lane >> 4, q4 = (lane & 15) * 4;
    for (int rel = 0; rel < 2; rel++) {
        const float* f1 = rel ? a.f1n : a.f1p;
        const float* f2 = rel ? a.f2n : a.f2p;
        const float* S  = rel ? a.S_neg : a.S_pos;
        const float* P  = rel ? a.P_neg : a.P_pos;
        const float* b  = rel ? a.neg_b : a.pos_b;
        float* G        = a.G + (size_t)rel * KN * KD;
        int count = rel ? c1 : c0;
        int countR = (count + 3) & ~3;
        float f2i = f2[h * KN + i];
        float m = -1e30f;
        for (int k = lane; k < count; k += 64) {
            int j = jl[rel][k];
            float x = f1[h * KN + j] + f2i;
            x = (x > 0.0f) ? x : 0.2f * x;      // leaky_relu 0.2
            lg[h][k] = x;
            m = fmaxf(m, x);
        }
        m = wave_max(m);
        float ps = 0.0f;
        for (int k = lane; k < count; k += 64) {
            float e = __expf(lg[h][k] - m);
            lg[h][k] = e;
            ps += e;
        }
        float denom = wave_sum(ps);
        for (int k2 = count + lane; k2 < countR; k2 += 64) lg[h][k2] = 0.0f;
        const float* Sh4 = S + h * KF + q4;
        float ax = 0.0f, ay = 0.0f, az = 0.0f, aw = 0.0f;
        for (int k = 0; k < countR; k += 4) {
            int j = jl[rel][k + g];
            float wgt = lg[h][k + g];
            float4 sv = *reinterpret_cast<const float4*>(&Sh4[(size_t)j * KD]);
            ax += wgt * sv.x; ay += wgt * sv.y; az += wgt * sv.z; aw += wgt * sv.w;
        }
        #pragma unroll
        for (int o = 16; o < 64; o <<= 1) {
            ax += __shfl_xor(ax, o, 64); ay += __shfl_xor(ay, o, 64);
            az += __shfl_xor(az, o, 64); aw += __shfl_xor(aw, o, 64);
        }
        if (g == 0) {
            float inv = count ? (1.0f / denom) : 0.0f;
            int col = h * KF + q4;
            size_t idx = (size_t)i * KD + col;
            float4 pv = *reinterpret_cast<const float4*>(&P[idx]);
            float4 o4;
            o4.x = ax * inv + b[col + 0] + pv.x;
            o4.y = ay * inv + b[col + 1] + pv.y;
            o4.z = az * inv + b[col + 2] + pv.z;
            o4.w = aw * inv + b[col + 3] + pv.w;
            *reinterpret_cast<float4*>(&G[idx]) = o4;
        }
    }
}

// ---- K3: tailcombine. Block b owns rows [b*16, b*16+16) end-to-end:
//   5 GEMM passes (psup, ch1 | nsup, ch2 | ch0) with A staged once per
//   operand, wlog dots reduced block-locally, beta + X computed inline.
//   psup/nsup live in registers only; combine kernel eliminated. ----------
__global__ __launch_bounds__(256, 2) void tailcombine_kernel(Args a) {
    __shared__ alignas(16) short A_s[16][264];     // 8.4 KB: A rows bf16 [row][k]
    __shared__ alignas(16) short B_s[256][40];     // 20 KB: B chunk bf16 [col][k-kt]
    __shared__ float wrow[3][16];
    __shared__ float beta[16][3];
    int r0 = blockIdx.x * 16;
    int t = threadIdx.x, w = t >> 6, lane = t & 63;
    int m16 = lane & 15, kq = lane >> 4;
    if (t < 48) ((float*)wrow)[t] = 0.0f;

    // stage A: 16 rows x 256 cols f32 -> bf16 LDS. thread: row t>>4, cols (t&15)*16..
    auto stageA = [&](const float* rowbase) {
        int row = t >> 4, c0 = (t & 15) * 16;
        const float* p = &rowbase[(size_t)row * KD + c0];
        float4 f0 = *(const float4*)(p);
        float4 f1 = *(const float4*)(p + 4);
        float4 f2 = *(const float4*)(p + 8);
        float4 f3 = *(const float4*)(p + 12);
        short8 v0, v1;
        v0[0] = f2bs(f0.x); v0[1] = f2bs(f0.y); v0[2] = f2bs(f0.z); v0[3] = f2bs(f0.w);
        v0[4] = f2bs(f1.x); v0[5] = f2bs(f1.y); v0[6] = f2bs(f1.z); v0[7] = f2bs(f1.w);
        v1[0] = f2bs(f2.x); v1[1] = f2bs(f2.y); v1[2] = f2bs(f2.z); v1[3] = f2bs(f2.w);
        v1[4] = f2bs(f3.x); v1[5] = f2bs(f3.y); v1[6] = f2bs(f3.z); v1[7] = f2bs(f3.w);
        *(short8*)&A_s[row][c0] = v0;
        *(short8*)&A_s[row][c0 + 8] = v1;
    };
    // GEMM pass: C[16 x 256] = A_s @ B, wave w's acc covers cols w*64..w*64+64
    auto gemmPass = [&](const float* __restrict__ B, floatx4* acc) {
        for (int kt = 0; kt < KD; kt += 32) {
            // stage B rows [kt,kt+32) x 256 cols, transposed: B_s[col][k-kt]
            // thread t = col; 4 groups of 8 k each
            #pragma unroll
            for (int g = 0; g < 4; g++) {
                short8 bv;
                #pragma unroll
                for (int u = 0; u < 8; u++)
                    bv[u] = f2bs(B[(size_t)(kt + g * 8 + u) * KD + t]);
                *(short8*)&B_s[t][g * 8] = bv;
            }
            __syncthreads();
            short8 af = *(short8*)&A_s[m16][kt + kq * 8];
            #pragma unroll
            for (int nb = 0; nb < 4; nb++) {
                short8 bf = *(short8*)&B_s[w * 64 + nb * 16 + m16][kq * 8];
                acc[nb] = __builtin_amdgcn_mfma_f32_16x16x32_bf16(af, bf, acc[nb], 0, 0, 0);
            }
            __syncthreads();
        }
    };
    // wlog dot: rows kq*4+r, wave's 64 cols; tanh(acc+fb[col]) . w2[col]
    auto wDot = [&](floatx4* acc, const float* __restrict__ fb, int ch) {
        float p[4] = {0, 0, 0, 0};
        #pragma unroll
        for (int nb = 0; nb < 4; nb++) {
            int col = w * 64 + nb * 16 + m16;
            float fbv = fb[col], w2v = a.sem_w2[col];
            #pragma unroll
            for (int r = 0; r < 4; r++) {
                float v = acc[nb][r] + fbv;
                float vc = fminf(fmaxf(v, -9.0f), 9.0f);
                float ex = __expf(2.0f * vc);
                p[r] += ((ex - 1.0f) / (ex + 1.0f)) * w2v;
            }
        }
        #pragma unroll
        for (int r = 0; r < 4; r++) {
            float pr = p[r];
            #pragma unroll
            for (int o = 1; o < 16; o <<= 1) pr += __shfl_xor(pr, o, 64);
            if (m16 == 0) atomicAdd(&wrow[ch][kq * 4 + r], pr);
        }
    };

    floatx4 accP[4] = {{0,0,0,0},{0,0,0,0},{0,0,0,0},{0,0,0,0}};
    floatx4 accN[4] = {{0,0,0,0},{0,0,0,0},{0,0,0,0},{0,0,0,0}};
    floatx4 accW[4];

    // A = Gp rows
    stageA(a.G + (size_t)r0 * KD);
    gemmPass(a.mlp_pos_w, accP);                                // psup (regs)
    #pragma unroll
    for (int nb = 0; nb < 4; nb++) accW[nb] = floatx4{0,0,0,0};
    gemmPass(a.M0Wp, accW);  wDot(accW, a.fbp, 1);              // wlog ch1
    __syncthreads();
    // A = Gn rows
    stageA(a.G + (size_t)(KN + r0) * KD);
    gemmPass(a.mlp_neg_w, accN);                                // nsup (regs)
    #pragma unroll
    for (int nb = 0; nb < 4; nb++) accW[nb] = floatx4{0,0,0,0};
    gemmPass(a.M0Wn, accW);  wDot(accW, a.fbn, 2);              // wlog ch2
    __syncthreads();
    // A = sup rows
    stageA(a.sup + (size_t)r0 * KD);
    #pragma unroll
    for (int nb = 0; nb < 4; nb++) accW[nb] = floatx4{0,0,0,0};
    gemmPass(a.sem_w1, accW);  wDot(accW, a.sem_b1, 0);         // wlog ch0
    __syncthreads();
    // beta per row
    if (t < 16) {
        float w0 = wrow[0][t], w1 = wrow[1][t], w2l = wrow[2][t];
        float mm = fmaxf(w0, fmaxf(w1, w2l));
        float e0 = __expf(w0 - mm), e1 = __expf(w1 - mm), e2 = __expf(w2l - mm);
        float inv = 1.0f / (e0 + e1 + e2);
        beta[t][0] = e0 * inv; beta[t][1] = e1 * inv; beta[t][2] = e2 * inv;
    }
    __syncthreads();
    // X = b0*sup + b1*(psup+pb) + b2*(nsup+nb); store + colsum atomics
    #pragma unroll
    for (int nb = 0; nb < 4; nb++) {
        int col = w * 64 + nb * 16 + m16;
        float pb = a.mlp_pos_b[col], nbias = a.mlp_neg_b[col];
        #pragma unroll
        for (int r = 0; r < 4; r++) {
            int row = kq * 4 + r;
            size_t idx = (size_t)(r0 + row) * KD + col;
            float b0 = beta[row][0], b1 = beta[row][1], b2 = beta[row][2];
            float xv = b0 * a.sup[idx] + b1 * (accP[nb][r] + pb) + b2 * (accN[nb][r] + nbias);
            a.X[idx] = xv;
            atomicAdd(&a.colsum[((r0 + row) & (NCS - 1)) * KD + col], xv);
        }
    }
}

// ---------------- K4: PairNorm PN-SI + store ----------------
__global__ __launch_bounds__(256) void final_kernel(Args a) {
    __shared__ float sb[4];
    int n = blockIdx.x, d = threadIdx.x;
    float cs = 0.0f;
    #pragma unroll
    for (int r = 0; r < NCS; r++) cs += a.colsum[r * KD + d];
    float mean = cs * (1.0f / KN);
    float xc = a.X[(size_t)n * KD + d] - mean;
    int wv = d >> 6, lane = d & 63;
    float s = wave_sum(xc * xc);
    if (lane == 0) sb[wv] = s;
    __syncthreads();
    float ss = sb[0] + sb[1] + sb[2] + sb[3];
    a.out[(size_t)n * KD + d] = xc * rsqrtf(1e-6f + ss);
}

// ---------------- host ----------------
extern "C" void kernel_launch(void* const* d_in, const int* in_sizes, int n_in,
                              void* d_out, int out_size, void* d_ws, size_t ws_size,
                              hipStream_t stream) {
    typedef const float* fp;
    Args a;
    a.emb    = (fp)d_in[0];
    a.y      = (fp)d_in[1];
    a.adj    = (fp)d_in[2];
    a.pos_w  = (fp)d_in[3];  a.pos_wu = (fp)d_in[4];  a.pos_wv = (fp)d_in[5];
    a.pos_b  = (fp)d_in[6];  a.pos_pw = (fp)d_in[7];  a.pos_pb = (fp)d_in[8];
    a.neg_w  = (fp)d_in[9];  a.neg_wu = (fp)d_in[10]; a.neg_wv = (fp)d_in[11];
    a.neg_b  = (fp)d_in[12]; a.neg_pw = (fp)d_in[13]; a.neg_pb = (fp)d_in[14];
    a.self_w = (fp)d_in[15]; a.self_b = (fp)d_in[16];
    a.mlp_pos_w = (fp)d_in[17]; a.mlp_pos_b = (fp)d_in[18];
    a.mlp_neg_w = (fp)d_in[19]; a.mlp_neg_b = (fp)d_in[20];
    a.sem_w1 = (fp)d_in[21]; a.sem_b1 = (fp)d_in[22]; a.sem_w2 = (fp)d_in[23];
    a.out = (float*)d_out;

    char* ws = (char*)d_ws;
    size_t off = 0;
    auto alloc = [&](size_t sz) -> char* {
        char* p = ws + off;
        off += (sz + 511) & ~(size_t)511;
        return p;
    };
    const size_t MAT = (size_t)KN * KD * 4;   // 2 MB

    a.ycs    = (float*)alloc((size_t)KN * KT * 4);
    a.code   = (unsigned char*)alloc((size_t)KN * KN);
    a.S_pos  = (float*)alloc(MAT);
    a.S_neg  = (float*)alloc(MAT);
    a.P_pos  = (float*)alloc(MAT);
    a.P_neg  = (float*)alloc(MAT);
    a.sup    = (float*)alloc(MAT);
    a.G      = (float*)alloc(2 * MAT);        // G_pos|G_neg contiguous
    a.X      = (float*)alloc(MAT);
    a.colsum = (float*)alloc((size_t)NCS * KD * 4);
    a.f1p    = (float*)alloc((size_t)KH * KN * 4);
    a.f2p    = (float*)alloc((size_t)KH * KN * 4);
    a.f1n    = (float*)alloc((size_t)KH * KN * 4);
    a.f2n    = (float*)alloc((size_t)KH * KN * 4);
    a.M0Wp   = (float*)alloc((size_t)KD * KD * 4);
    a.M0Wn   = (float*)alloc((size_t)KD * KD * 4);
    a.fbp    = (float*)alloc(KD * 4);
    a.fbn    = (float*)alloc(KD * 4);

    setup_kernel<<<512, 256, 0, stream>>>(a.y, a.ycs);
    phase1_kernel<<<1203, 256, 0, stream>>>(a);
    attn_kernel<<<KN, 256, 0, stream>>>(a);
    tailcombine_kernel<<<KN / 16, 256, 0, stream>>>(a);
    final_kernel<<<KN, 256, 0, stream>>>(a);
}

// Round 10
// 162.913 us; speedup vs baseline: 1.1794x; 1.1794x over previous
//
#include <hip/hip_runtime.h>
#include <hip/hip_bf16.h>

#define KN  2048   // nodes
#define KD  256    // emb dim = HF
#define KH  4      // heads
#define KF  64     // feat/head
#define KT  64     // time steps
#define NCS 32     // colsum partial buffers
#define MAXE 256

typedef __attribute__((ext_vector_type(8))) short short8;
typedef __attribute__((ext_vector_type(4))) float floatx4;

struct Args {
    const float *y, *adj, *emb;
    const float *pos_w, *pos_wu, *pos_wv, *pos_b, *pos_pw, *pos_pb;
    const float *neg_w, *neg_wu, *neg_wv, *neg_b, *neg_pw, *neg_pb;
    const float *self_w, *self_b;
    const float *mlp_pos_w, *mlp_pos_b, *mlp_neg_w, *mlp_neg_b;
    const float *sem_w1, *sem_b1, *sem_w2;
    float* out;
    unsigned char* code;
    float *ycs, *S_pos, *S_neg, *P_pos, *P_neg, *sup, *G, *psup, *X, *colsum;
    float *f1p, *f2p, *f1n, *f2n, *M0Wp, *M0Wn, *fbp, *fbn, *wlog;
};

// ---------------- helpers ----------------
__device__ __forceinline__ float wave_sum(float v) {
    #pragma unroll
    for (int o = 32; o > 0; o >>= 1) v += __shfl_xor(v, o, 64);
    return v;
}
__device__ __forceinline__ float wave_max(float v) {
    #pragma unroll
    for (int o = 32; o > 0; o >>= 1) v = fmaxf(v, __shfl_xor(v, o, 64));
    return v;
}
__device__ __forceinline__ short f2bs(float x) {
    union { __hip_bfloat16 h; short s; } u;
    u.h = __float2bfloat16(x);
    return u.s;
}

// ---------------- K0: setup = ycs normalize ----------------
__global__ __launch_bounds__(256) void setup_kernel(const float* __restrict__ y,
                                                    float* __restrict__ ycs) {
    int w = threadIdx.x >> 6, lane = threadIdx.x & 63;
    int n = blockIdx.x * 4 + w;
    float v = y[n * KT + lane];
    float mean = wave_sum(v) * (1.0f / KT);
    float yc = v - mean;
    float ss = wave_sum(yc * yc);
    ycs[n * KT + lane] = yc * rsqrtf(ss * (1.0f / (KT - 1)));
}

// ---------------- corr body: upper-tri 64x64 tile, writes (i,j) AND (j,i) --
__device__ __forceinline__ void corr_body(const float* __restrict__ ycs,
                                          const float* __restrict__ adj,
                                          unsigned char* __restrict__ code,
                                          int blk, char* smem) {
    float (*As)[68] = (float(*)[68])smem;            // 16x68 f32
    float (*Bs)[68] = (float(*)[68])(smem + 4352);
    int bi = 0, rem = blk;
    while (rem >= 32 - bi) { rem -= 32 - bi; bi++; }
    int bj = bi + rem;
    int i0 = bi * 64, j0 = bj * 64;
    int t = threadIdx.x;
    int tx = t & 15, ty = t >> 4;
    int ar = t >> 2, ac = (t & 3) * 4;
    float acc[4][4] = {};
    for (int kt = 0; kt < KT; kt += 16) {
        float4 a4 = *reinterpret_cast<const float4*>(&ycs[(size_t)(i0 + ar) * KT + kt + ac]);
        float4 b4 = *reinterpret_cast<const float4*>(&ycs[(size_t)(j0 + ar) * KT + kt + ac]);
        As[ac + 0][ar] = a4.x; As[ac + 1][ar] = a4.y; As[ac + 2][ar] = a4.z; As[ac + 3][ar] = a4.w;
        Bs[ac + 0][ar] = b4.x; Bs[ac + 1][ar] = b4.y; Bs[ac + 2][ar] = b4.z; Bs[ac + 3][ar] = b4.w;
        __syncthreads();
        #pragma unroll
        for (int kk = 0; kk < 16; kk++) {
            float4 av = *reinterpret_cast<const float4*>(&As[kk][ty * 4]);
            float4 bv = *reinterpret_cast<const float4*>(&Bs[kk][tx * 4]);
            float a4v[4] = {av.x, av.y, av.z, av.w};
            float b4v[4] = {bv.x, bv.y, bv.z, bv.w};
            #pragma unroll
            for (int ii = 0; ii < 4; ii++)
                #pragma unroll
                for (int jj = 0; jj < 4; jj++) acc[ii][jj] += a4v[ii] * b4v[jj];
        }
        __syncthreads();
    }
    #pragma unroll
    for (int ii = 0; ii < 4; ii++) {
        int i = i0 + ty * 4 + ii;
        int jb = j0 + tx * 4;
        float4 av4 = *reinterpret_cast<const float4*>(&adj[(size_t)i * KN + jb]);
        float a4v[4] = {av4.x, av4.y, av4.z, av4.w};
        uchar4 cc;
        unsigned char* c = (unsigned char*)&cc;
        #pragma unroll
        for (int jj = 0; jj < 4; jj++)
            c[jj] = (a4v[jj] != 0.0f) ? ((acc[ii][jj] >= 0.1f) ? 1 : 2) : 0;
        *reinterpret_cast<uchar4*>(&code[(size_t)i * KN + jb]) = cc;
    }
    if (bi != bj) {
        #pragma unroll
        for (int jj = 0; jj < 4; jj++) {
            int j = j0 + tx * 4 + jj;
            int ib = i0 + ty * 4;
            float4 av4 = *reinterpret_cast<const float4*>(&adj[(size_t)j * KN + ib]);
            float a4v[4] = {av4.x, av4.y, av4.z, av4.w};
            uchar4 cc;
            unsigned char* c = (unsigned char*)&cc;
            #pragma unroll
            for (int ii = 0; ii < 4; ii++)
                c[ii] = (a4v[ii] != 0.0f) ? ((acc[ii][jj] >= 0.1f) ? 1 : 2) : 0;
            *reinterpret_cast<uchar4*>(&code[(size_t)j * KN + ib]) = cc;
        }
    }
}

// ---------------- MFMA bf16 GEMM body: 64x64 C tile, K=256 ----------------
// A f32 [M,lda] row-major, B f32 [256,ldb] row-major (tile at bn), C f32.
// WCH >= 0: don't store C; instead accumulate wlog[row][WCH] += tanh(v)*w2[col]
// (one non-returning atomicAdd per row per tile). TANH applies tanh before C store.
template <bool TANH, int WCH>
__device__ __forceinline__ void mfma_gemm_body(
    const float* __restrict__ A, int lda, int bm,
    const float* __restrict__ B, int ldb, int bn,
    const float* __restrict__ bias,
    float* __restrict__ C, int ldc, int cn,
    float* __restrict__ f1h, float* __restrict__ f2h,
    const float* __restrict__ wu_h, const float* __restrict__ wv_h,
    float* __restrict__ wlogp, const float* __restrict__ w2,
    char* smem)
{
    short* As = (short*)smem;            // [64][40] bf16 (row m, col k)
    short* Bs = (short*)(smem + 5120);   // [64][40] bf16 (row n, col k) transposed
    int t = threadIdx.x;
    int w = t >> 6, lane = t & 63;
    int m16 = lane & 15, kq = lane >> 4;
    floatx4 acc0 = {0,0,0,0}, acc1 = {0,0,0,0}, acc2 = {0,0,0,0}, acc3 = {0,0,0,0};
    int ar = t >> 2, acq = (t & 3) * 8;     // A stage: row 0..63, k-offset {0,8,16,24}
    int bnn = t & 63, bkg = (t >> 6) * 8;   // B stage: col 0..63, k-group {0,8,16,24}
    for (int kt = 0; kt < KD; kt += 32) {
        const float* pa = &A[(size_t)(bm + ar) * lda + kt + acq];
        float4 a0 = *(const float4*)pa;
        float4 a1 = *(const float4*)(pa + 4);
        short8 av;
        av[0] = f2bs(a0.x); av[1] = f2bs(a0.y); av[2] = f2bs(a0.z); av[3] = f2bs(a0.w);
        av[4] = f2bs(a1.x); av[5] = f2bs(a1.y); av[6] = f2bs(a1.z); av[7] = f2bs(a1.w);
        const float* pb = &B[(size_t)(kt + bkg) * ldb + bn + bnn];
        short8 bv;
        #pragma unroll
        for (int u = 0; u < 8; u++) bv[u] = f2bs(pb[(size_t)u * ldb]);
        __syncthreads();   // previous iteration's frag reads complete
        *(short8*)&As[ar * 40 + acq] = av;
        *(short8*)&Bs[bnn * 40 + bkg] = bv;
        __syncthreads();
        short8 af  = *(short8*)&As[(w * 16 + m16) * 40 + kq * 8];
        short8 bf0 = *(short8*)&Bs[( 0 + m16) * 40 + kq * 8];
        short8 bf1 = *(short8*)&Bs[(16 + m16) * 40 + kq * 8];
        short8 bf2 = *(short8*)&Bs[(32 + m16) * 40 + kq * 8];
        short8 bf3 = *(short8*)&Bs[(48 + m16) * 40 + kq * 8];
        acc0 = __builtin_amdgcn_mfma_f32_16x16x32_bf16(af, bf0, acc0, 0, 0, 0);
        acc1 = __builtin_amdgcn_mfma_f32_16x16x32_bf16(af, bf1, acc1, 0, 0, 0);
        acc2 = __builtin_amdgcn_mfma_f32_16x16x32_bf16(af, bf2, acc2, 0, 0, 0);
        acc3 = __builtin_amdgcn_mfma_f32_16x16x32_bf16(af, bf3, acc3, 0, 0, 0);
    }
    // epilogue: C/D layout col=lane&15, row=(lane>>4)*4+reg
    int row0 = bm + w * 16 + kq * 4;
    floatx4 accs[4] = {acc0, acc1, acc2, acc3};
    if (WCH >= 0) {
        // wlog channel: partial = sum_col tanh(v)*w2[cn+col], reduce over m16
        float w2c[4];
        #pragma unroll
        for (int nb = 0; nb < 4; nb++) w2c[nb] = w2[cn + nb * 16 + m16];
        #pragma unroll
        for (int r = 0; r < 4; r++) {
            float p = 0.0f;
            #pragma unroll
            for (int nb = 0; nb < 4; nb++) {
                float v = accs[nb][r] + bias[nb * 16 + m16];
                float vc = fminf(fmaxf(v, -9.0f), 9.0f);
                float ex = __expf(2.0f * vc);
                p += ((ex - 1.0f) / (ex + 1.0f)) * w2c[nb];
            }
            #pragma unroll
            for (int o = 1; o < 16; o <<= 1) p += __shfl_xor(p, o, 64);
            if (m16 == 0) atomicAdd(&wlogp[(size_t)(row0 + r) * 4 + WCH], p);
        }
        return;
    }
    #pragma unroll
    for (int nb = 0; nb < 4; nb++) {
        #pragma unroll
        for (int r = 0; r < 4; r++) {
            int col = nb * 16 + m16;
            float v = accs[nb][r] + (bias ? bias[col] : 0.0f);
            if (TANH) {
                float vc = fminf(fmaxf(v, -9.0f), 9.0f);
                float ex = __expf(2.0f * vc);
                v = (ex - 1.0f) / (ex + 1.0f);
            }
            C[(size_t)(row0 + r) * ldc + cn + col] = v;
        }
    }
    if (f1h) {  // fused f1/f2: dot each row with wu/wv over this head's 64 cols
        float wuv[4], wvv[4];
        #pragma unroll
        for (int nb = 0; nb < 4; nb++) { wuv[nb] = wu_h[nb * 16 + m16]; wvv[nb] = wv_h[nb * 16 + m16]; }
        #pragma unroll
        for (int r = 0; r < 4; r++) {
            float p1 = accs[0][r] * wuv[0] + accs[1][r] * wuv[1] + accs[2][r] * wuv[2] + accs[3][r] * wuv[3];
            float p2 = accs[0][r] * wvv[0] + accs[1][r] * wvv[1] + accs[2][r] * wvv[2] + accs[3][r] * wvv[3];
            #pragma unroll
            for (int o = 1; o < 16; o <<= 1) {
                p1 += __shfl_xor(p1, o, 64);
                p2 += __shfl_xor(p2, o, 64);
            }
            if (m16 == 0) { f1h[row0 + r] = p1; f2h[row0 + r] = p2; }
        }
    }
}

// ---------------- fused bias unit: fb = mlp_b @ sem_w1 + sem_b1 ---------
__device__ __forceinline__ void fb_unit(const float* __restrict__ mb,
                                        const float* __restrict__ w1,
                                        const float* __restrict__ b1,
                                        float* __restrict__ fb) {
    int j = threadIdx.x;
    float acc = b1[j];
    for (int k = 0; k < KD; k++) acc = fmaf(mb[k], w1[(size_t)k * KD + j], acc);
    fb[j] = acc;
}

// ---- K1: phase1 = corr(528) + emb GEMMs(640) + M0W(32) + fb(2) + zero(1) --
__global__ __launch_bounds__(256, 4) void phase1_kernel(Args a) {
    __shared__ alignas(16) char smem[10240];
    int blk = blockIdx.x;
    if (blk < 528) { corr_body(a.ycs, a.adj, a.code, blk, smem); return; }
    if (blk < 1168) {
        int b = blk - 528;             // 0..639: 5 emb GEMMs x 4 coltiles x 32 rowtiles
        int tn = b % 20, tm = b / 20;
        int buf = tn >> 2, coloff = (tn & 3) * 64, h = tn & 3;
        const float* B; const float* bias = nullptr; float* C;
        float *f1h = nullptr, *f2h = nullptr;
        const float *wu = nullptr, *wv = nullptr;
        if (buf == 0) {
            B = a.pos_w; C = a.S_pos;
            f1h = a.f1p + h * KN; f2h = a.f2p + h * KN;
            wu = a.pos_wu + h * KF; wv = a.pos_wv + h * KF;
        } else if (buf == 1) {
            B = a.neg_w; C = a.S_neg;
            f1h = a.f1n + h * KN; f2h = a.f2n + h * KN;
            wu = a.neg_wu + h * KF; wv = a.neg_wv + h * KF;
        } else if (buf == 2) { B = a.pos_pw; bias = a.pos_pb + coloff; C = a.P_pos; }
        else if (buf == 3)   { B = a.neg_pw; bias = a.neg_pb + coloff; C = a.P_neg; }
        else                 { B = a.self_w; bias = a.self_b + coloff; C = a.sup; }
        mfma_gemm_body<false, -1>(a.emb, KD, tm * 64, B, KD, coloff, bias,
                                  C, KD, coloff, f1h, f2h, wu, wv,
                                  nullptr, nullptr, smem);
        return;
    }
    if (blk < 1184) {   // M0Wp = mlp_pos_w @ sem_w1
        int v = blk - 1168;
        mfma_gemm_body<false, -1>(a.mlp_pos_w, KD, (v >> 2) * 64, a.sem_w1, KD, (v & 3) * 64,
                                  nullptr, a.M0Wp, KD, (v & 3) * 64,
                                  nullptr, nullptr, nullptr, nullptr,
                                  nullptr, nullptr, smem);
        return;
    }
    if (blk < 1200) {   // M0Wn = mlp_neg_w @ sem_w1
        int v = blk - 1184;
        mfma_gemm_body<false, -1>(a.mlp_neg_w, KD, (v >> 2) * 64, a.sem_w1, KD, (v & 3) * 64,
                                  nullptr, a.M0Wn, KD, (v & 3) * 64,
                                  nullptr, nullptr, nullptr, nullptr,
                                  nullptr, nullptr, smem);
        return;
    }
    if (blk == 1200) { fb_unit(a.mlp_pos_b, a.sem_w1, a.sem_b1, a.fbp); return; }
    if (blk == 1201) { fb_unit(a.mlp_neg_b, a.sem_w1, a.sem_b1, a.fbn); return; }
    // blk == 1202: zero colsum + wlog
    for (int j = threadIdx.x; j < NCS * KD; j += 256) a.colsum[j] = 0.0f;
    for (int j = threadIdx.x; j < KN * 4; j += 256) a.wlog[j] = 0.0f;
}

// ---------------- K2: sparse GAT row, block per i, both rels, wave = head --
__global__ __launch_bounds__(256) void attn_kernel(Args a) {
    __shared__ alignas(16) int jl[2][MAXE];
    __shared__ alignas(16) float lg[KH][MAXE];
    __shared__ int cnt[2];
    int i = blockIdx.x;
    int w = threadIdx.x >> 6, lane = threadIdx.x & 63;
    if (threadIdx.x < 2) cnt[threadIdx.x] = 0;
    __syncthreads();
    // cooperative scan: wave w covers columns [w*512, w*512+512), both rels
    #pragma unroll
    for (int it = 0; it < 2; it++) {
        int base = w * 512 + it * 256;
        uchar4 cv = *reinterpret_cast<const uchar4*>(&a.code[(size_t)i * KN + base + lane * 4]);
        const unsigned char* ce = (const unsigned char*)&cv;
        #pragma unroll
        for (int e = 0; e < 4; e++) {
            #pragma unroll
            for (int rel = 0; rel < 2; rel++) {
                bool pr = (ce[e] == (rel ? (unsigned char)2 : (unsigned char)1));
                unsigned long long bal = __ballot(pr);
                int tot = __popcll(bal);
                int basepos = 0;
                if (lane == 0 && tot) basepos = atomicAdd(&cnt[rel], tot);
                basepos = __shfl(basepos, 0, 64);
                if (pr) {
                    int idx = basepos + __popcll(bal & ((1ull << lane) - 1ull));
                    if (idx < MAXE) jl[rel][idx] = base + lane * 4 + e;
                }
            }
        }
    }
    __syncthreads();
    int c0 = cnt[0]; if (c0 > MAXE) c0 = MAXE;
    int c1 = cnt[1]; if (c1 > MAXE) c1 = MAXE;
    if (threadIdx.x < 4) {
        int cR = (c0 + 3) & ~3;
        if (c0 + threadIdx.x < cR) jl[0][c0 + threadIdx.x] = 0;
    } else if (threadIdx.x < 8) {
        int l2 = threadIdx.x - 4;
        int cR = (c1 + 3) & ~3;
        if (c1 + l2 < cR) jl[1][c1 + l2] = 0;
    }
    __syncthreads();
    int h = w;                                  // one wave per head
    int g = lane >> 4, q4 = (lane & 15) * 4;
    for (int rel = 0; rel < 2; rel++) {
        const float* f1 = rel ? a.f1n : a.f1p;
        const float* f2 = rel ? a.f2n : a.f2p;
        const float* S  = rel ? a.S_neg : a.S_pos;
        const float* P  = rel ? a.P_neg : a.P_pos;
        const float* b  = rel ? a.neg_b : a.pos_b;
        float* G        = a.G + (size_t)rel * KN * KD;
        int count = rel ? c1 : c0;
        int countR = (count + 3) & ~3;
        float f2i = f2[h * KN + i];
        float m = -1e30f;
        for (int k = lane; k < count; k += 64) {
            int j = jl[rel][k];
            float x = f1[h * KN + j] + f2i;
            x = (x > 0.0f) ? x : 0.2f * x;      // leaky_relu 0.2
            lg[h][k] = x;
            m = fmaxf(m, x);
        }
        m = wave_max(m);
        float ps = 0.0f;
        for (int k = lane; k < count; k += 64) {
            float e = __expf(lg[h][k] - m);
            lg[h][k] = e;
            ps += e;
        }
        float denom = wave_sum(ps);
        for (int k2 = count + lane; k2 < countR; k2 += 64) lg[h][k2] = 0.0f;
        // gather: 16 lanes x float4 per j, 4 j's per iteration
        const float* Sh4 = S + h * KF + q4;
        float ax = 0.0f, ay = 0.0f, az = 0.0f, aw = 0.0f;
        for (int k = 0; k < countR; k += 4) {
            int j = jl[rel][k + g];
            float wgt = lg[h][k + g];
            float4 sv = *reinterpret_cast<const float4*>(&Sh4[(size_t)j * KD]);
            ax += wgt * sv.x; ay += wgt * sv.y; az += wgt * sv.z; aw += wgt * sv.w;
        }
        #pragma unroll
        for (int o = 16; o < 64; o <<= 1) {
            ax += __shfl_xor(ax, o, 64); ay += __shfl_xor(ay, o, 64);
            az += __shfl_xor(az, o, 64); aw += __shfl_xor(aw, o, 64);
        }
        if (g == 0) {
            float inv = count ? (1.0f / denom) : 0.0f;
            int col = h * KF + q4;
            size_t idx = (size_t)i * KD + col;
            float4 pv = *reinterpret_cast<const float4*>(&P[idx]);
            float4 o4;
            o4.x = ax * inv + b[col + 0] + pv.x;
            o4.y = ay * inv + b[col + 1] + pv.y;
            o4.z = az * inv + b[col + 2] + pv.z;
            o4.w = aw * inv + b[col + 3] + pv.w;
            *reinterpret_cast<float4*>(&G[idx]) = o4;
        }
    }
}

// ---- K3: tail = psup|nsup(256) + wlog ch0(128) + ch1(128) + ch2(128) -----
__global__ __launch_bounds__(256, 4) void tail_kernel(Args a) {
    __shared__ alignas(16) char smem[10240];
    int u = blockIdx.x;
    if (u < 256) {        // psup|nsup = [Gp;Gn] @ mlp_{pos|neg}_w + b
        int bx = u & 3, bm = (u >> 2) * 64;
        bool sel = bm >= KN;
        mfma_gemm_body<false, -1>(a.G, KD, bm, sel ? a.mlp_neg_w : a.mlp_pos_w, KD, bx * 64,
                                  (sel ? a.mlp_neg_b : a.mlp_pos_b) + bx * 64,
                                  a.psup, KD, bx * 64,
                                  nullptr, nullptr, nullptr, nullptr,
                                  nullptr, nullptr, smem);
    } else if (u < 384) { // wlog ch0: tanh(sup @ sem_w1 + sem_b1) . w2
        int v = u - 256; int bx = v & 3, bm = (v >> 2) * 64;
        mfma_gemm_body<true, 0>(a.sup, KD, bm, a.sem_w1, KD, bx * 64, a.sem_b1 + bx * 64,
                                nullptr, KD, bx * 64,
                                nullptr, nullptr, nullptr, nullptr,
                                a.wlog, a.sem_w2, smem);
    } else if (u < 512) { // wlog ch1: tanh(Gp @ M0Wp + fbp) . w2
        int v = u - 384; int bx = v & 3, bm = (v >> 2) * 64;
        mfma_gemm_body<true, 1>(a.G, KD, bm, a.M0Wp, KD, bx * 64, a.fbp + bx * 64,
                                nullptr, KD, bx * 64,
                                nullptr, nullptr, nullptr, nullptr,
                                a.wlog, a.sem_w2, smem);
    } else {              // wlog ch2: tanh(Gn @ M0Wn + fbn) . w2  (rows KN..2KN)
        int v = u - 512; int bx = v & 3, bm = KN + (v >> 2) * 64;
        mfma_gemm_body<true, 2>(a.G, KD, bm, a.M0Wn, KD, bx * 64, a.fbn + bx * 64,
                                nullptr, KD, bx * 64,
                                nullptr, nullptr, nullptr, nullptr,
                                a.wlog - (size_t)KN * 4, a.sem_w2, smem);
    }
}

// ---------------- K4: semantic blend + colsum partials ----------------
__global__ __launch_bounds__(256) void combine_kernel(Args a) {
    int n = blockIdx.x, d = threadIdx.x;
    size_t idx = (size_t)n * KD + d;
    float4 wl = *reinterpret_cast<const float4*>(&a.wlog[(size_t)n * 4]);
    float mm = fmaxf(wl.x, fmaxf(wl.y, wl.z));
    float e0 = __expf(wl.x - mm), e1 = __expf(wl.y - mm), e2 = __expf(wl.z - mm);
    float inv = 1.0f / (e0 + e1 + e2);
    float* nsup = a.psup + (size_t)KN * KD;
    float x = (e0 * inv) * a.sup[idx] + (e1 * inv) * a.psup[idx] + (e2 * inv) * nsup[idx];
    a.X[idx] = x;
    atomicAdd(&a.colsum[(n & (NCS - 1)) * KD + d], x);   // non-returning
}

// ---------------- K5: PairNorm PN-SI + store ----------------
__global__ __launch_bounds__(256) void final_kernel(Args a) {
    __shared__ float sb[4];
    int n = blockIdx.x, d = threadIdx.x;
    float cs = 0.0f;
    #pragma unroll
    for (int r = 0; r < NCS; r++) cs += a.colsum[r * KD + d];
    float mean = cs * (1.0f / KN);
    float xc = a.X[(size_t)n * KD + d] - mean;
    int wv = d >> 6, lane = d & 63;
    float s = wave_sum(xc * xc);
    if (lane == 0) sb[wv] = s;
    __syncthreads();
    float ss = sb[0] + sb[1] + sb[2] + sb[3];
    a.out[(size_t)n * KD + d] = xc * rsqrtf(1e-6f + ss);
}

// ---------------- host ----------------
extern "C" void kernel_launch(void* const* d_in, const int* in_sizes, int n_in,
                              void* d_out, int out_size, void* d_ws, size_t ws_size,
                              hipStream_t stream) {
    typedef const float* fp;
    Args a;
    a.emb    = (fp)d_in[0];
    a.y      = (fp)d_in[1];
    a.adj    = (fp)d_in[2];
    a.pos_w  = (fp)d_in[3];  a.pos_wu = (fp)d_in[4];  a.pos_wv = (fp)d_in[5];
    a.pos_b  = (fp)d_in[6];  a.pos_pw = (fp)d_in[7];  a.pos_pb = (fp)d_in[8];
    a.neg_w  = (fp)d_in[9];  a.neg_wu = (fp)d_in[10]; a.neg_wv = (fp)d_in[11];
    a.neg_b  = (fp)d_in[12]; a.neg_pw = (fp)d_in[13]; a.neg_pb = (fp)d_in[14];
    a.self_w = (fp)d_in[15]; a.self_b = (fp)d_in[16];
    a.mlp_pos_w = (fp)d_in[17]; a.mlp_pos_b = (fp)d_in[18];
    a.mlp_neg_w = (fp)d_in[19]; a.mlp_neg_b = (fp)d_in[20];
    a.sem_w1 = (fp)d_in[21]; a.sem_b1 = (fp)d_in[22]; a.sem_w2 = (fp)d_in[23];
    a.out = (float*)d_out;

    char* ws = (char*)d_ws;
    size_t off = 0;
    auto alloc = [&](size_t sz) -> char* {
        char* p = ws + off;
        off += (sz + 511) & ~(size_t)511;
        return p;
    };
    const size_t MAT = (size_t)KN * KD * 4;   // 2 MB

    a.ycs    = (float*)alloc((size_t)KN * KT * 4);
    a.code   = (unsigned char*)alloc((size_t)KN * KN);
    a.S_pos  = (float*)alloc(MAT);
    a.S_neg  = (float*)alloc(MAT);
    a.P_pos  = (float*)alloc(MAT);
    a.P_neg  = (float*)alloc(MAT);
    a.sup    = (float*)alloc(MAT);
    a.G      = (float*)alloc(2 * MAT);        // G_pos|G_neg contiguous
    a.psup   = (float*)alloc(2 * MAT);        // psup|nsup contiguous
    a.X      = (float*)alloc(MAT);
    a.colsum = (float*)alloc((size_t)NCS * KD * 4);
    a.f1p    = (float*)alloc((size_t)KH * KN * 4);
    a.f2p    = (float*)alloc((size_t)KH * KN * 4);
    a.f1n    = (float*)alloc((size_t)KH * KN * 4);
    a.f2n    = (float*)alloc((size_t)KH * KN * 4);
    a.M0Wp   = (float*)alloc((size_t)KD * KD * 4);
    a.M0Wn   = (float*)alloc((size_t)KD * KD * 4);
    a.fbp    = (float*)alloc(KD * 4);
    a.fbn    = (float*)alloc(KD * 4);
    a.wlog   = (float*)alloc((size_t)KN * 4 * 4);

    setup_kernel<<<512, 256, 0, stream>>>(a.y, a.ycs);
    phase1_kernel<<<1203, 256, 0, stream>>>(a);
    attn_kernel<<<KN, 256, 0, stream>>>(a);
    tail_kernel<<<640, 256, 0, stream>>>(a);
    combine_kernel<<<KN, 256, 0, stream>>>(a);
    final_kernel<<<KN, 256, 0, stream>>>(a);
}